// Round 16
// baseline (218.853 us; speedup 1.0000x reference)
//
#include <hip/hip_runtime.h>

#define TT 8
#define HH 24
#define WW 24
#define NN 4608            // T*H*W
#define CIN 256
#define N3 6760            // padded volume 10*26*26 (bf16 transposed layout rows)
#define KDIM 6912          // 27 taps * 256 ci
#define BK 64
#define KTILES 108         // KDIM / BK
#define NSPLIT 9
#define KT_PER 12          // KTILES / NSPLIT

typedef short short8 __attribute__((ext_vector_type(8)));
typedef short short4v __attribute__((ext_vector_type(4)));
typedef float f32x4  __attribute__((ext_vector_type(4)));
typedef int   i32x4  __attribute__((ext_vector_type(4)));
typedef unsigned int u32x4 __attribute__((ext_vector_type(4)));

#define MFMA16 __builtin_amdgcn_mfma_f32_16x16x32_bf16

__device__ __forceinline__ short f2bf(float f) {       // RNE f32 -> bf16 bits
    unsigned u = __float_as_uint(f);
    unsigned r = u + 0x7fffu + ((u >> 16) & 1u);
    return (short)(r >> 16);
}
__device__ __forceinline__ float bf2f(short s) {
    return __uint_as_float(((unsigned)(unsigned short)s) << 16);
}

__device__ __forceinline__ int n3_of(int n) {          // interior n -> padded row
    int t = n / (HH * WW), r = n % (HH * WW), h = r / WW, w = r % WW;
    return ((t + 1) * 26 + (h + 1)) * 26 + (w + 1);
}

// async 16B global -> LDS (wave-uniform LDS base + lane*16; global addr per-lane)
__device__ __forceinline__ void gload16(const void* gsrc, void* lds) {
    __builtin_amdgcn_global_load_lds(
        (const __attribute__((address_space(1))) void*)gsrc,
        (__attribute__((address_space(3))) void*)lds, 16, 0, 0);
}

// ---------------------------------------------------------------- merged prep
// grid (288, 7): sel 0-4 = weight repacks (LDS-staged coalesced), sel 5 =
// x transpose -> xbf3, sel 6 = zero pad rows of xbf3/h1b/h2b/h3b.
__global__ __launch_bounds__(256) void prep_k(
    const float* __restrict__ x,
    const float* __restrict__ w1, const float* __restrict__ w2,
    const float* __restrict__ w3, const float* __restrict__ wc,
    const float* __restrict__ wd,
    short* __restrict__ d1, short* __restrict__ d2,
    short* __restrict__ d3, short* __restrict__ dc, short* __restrict__ dd,
    short* __restrict__ xbf3, short* __restrict__ h1b)
{
    __shared__ char smem[27648];                       // 27KB union
    const int sel = blockIdx.y;

    if (sel < 5) {                                     // ---- weight repack ----
        if (blockIdx.x >= 256) return;
        const int o = blockIdx.x, ci = threadIdx.x;
        const float* w; short* dst; int Cout = 256;
        if      (sel == 0) { w = w1; dst = d1; }
        else if (sel == 1) { w = w2; dst = d2; }
        else if (sel == 2) { w = w3; dst = d3; }
        else if (sel == 3) { w = wc; dst = dc; }
        else               { w = wd; dst = dd; Cout = 81; if (o >= 128) return; }
        float* buf = (float*)smem;                     // one o-row [ci][k]
        if (o < Cout) {                                // coalesced row load
            const float* src = w + (size_t)o * KDIM;
            #pragma unroll
            for (int j = 0; j < 27; ++j)
                buf[j * 256 + ci] = src[j * 256 + ci];
        }
        __syncthreads();
        const int row = o & 127, y = o >> 7;
        #pragma unroll
        for (int k = 0; k < 27; ++k) {
            int K = k * 256 + ci;
            int kt = K >> 6, kk = K & 63;
            int slot = (kk >> 3) ^ (row & 7), e = kk & 7;
            size_t idx = ((size_t)(y * KTILES + kt)) * 8192 + row * 64 + slot * 8 + e;
            float v = (o < Cout) ? buf[ci * 27 + k] : 0.f;
            dst[idx] = f2bf(v);
        }
    } else if (sel == 5) {                             // ---- x transpose ----
        float (*T)[65] = (float(*)[65])smem;
        const int bx = blockIdx.x;                     // 288 = 72 x 4
        const int n0 = (bx % 72) * 64, ci0 = (bx / 72) * 64;
        const int lane = threadIdx.x & 63, wave = threadIdx.x >> 6;
        #pragma unroll
        for (int j = 0; j < 16; ++j) {
            int ci_l = wave * 16 + j;
            T[ci_l][lane] = x[(size_t)(ci0 + ci_l) * NN + n0 + lane];
        }
        __syncthreads();
        #pragma unroll
        for (int j = 0; j < 16; ++j) {
            int n_l = wave * 16 + j;
            xbf3[(size_t)n3_of(n0 + n_l) * 256 + ci0 + lane] = f2bf(T[lane][n_l]);
        }
    } else {                                           // ---- zero pad rows ----
        const int tid = threadIdx.x;
        for (int r = blockIdx.x * 27; r < min((int)(blockIdx.x * 27 + 27), N3); ++r) {
            int t3 = r / 676, rem = r % 676, h3 = rem / 26, w3 = rem % 26;
            bool interior = (t3 >= 1 && t3 <= 8 && h3 >= 1 && h3 <= 24 && w3 >= 1 && w3 <= 24);
            if (!interior && tid < 128) {
                ((unsigned*)(xbf3 + (size_t)r * 256))[tid] = 0;
                ((unsigned*)(h1b  + (size_t)r * 256))[tid] = 0;
                ((unsigned*)(h1b + 1730560 + (size_t)r * 256))[tid] = 0;   // h2b
                ((unsigned*)(h1b + 3461120 + (size_t)r * 256))[tid] = 0;   // h3b
            }
        }
    }
}

// ---------------------------------------------------------------- sampler
// S[k][n][ci] = bf16( sum_c w_c * xbf3[row_c][ci] ).
// Offsets-reduce folded in: records built from bf16 partials Poff (+ bias).
__global__ __launch_bounds__(256) void sample_k(
    const short* __restrict__ xbf3, const short* __restrict__ Poff,
    const float* __restrict__ dfb, short* __restrict__ S)
{
    __shared__ char recs[64 * 64];                     // 64 records x 64B
    const int k = blockIdx.y, n0 = blockIdx.x * 64;
    const int tid = threadIdx.x;

    if (tid < 64) {                                    // compute this block's records
        const int n = n0 + tid;
        const int t = n / (HH * WW), r = n % (HH * WW), h = r / WW, w2 = r % WW;
        const int ki = k / 9, kj = (k % 9) / 3, kl = k % 3;
        float po[3];
        #pragma unroll
        for (int d = 0; d < 3; ++d) {
            const int ch = k * 3 + d;
            float a = 0.f;
            #pragma unroll
            for (int s = 0; s < NSPLIT; ++s)
                a += bf2f(Poff[((size_t)(s * 128 + ch)) * NN + n]);
            po[d] = a + dfb[ch];
        }
        const float pt = (float)(t  + ki - 1) + po[0];
        const float ph = (float)(h  + kj - 1) + po[1];
        const float pw = (float)(w2 + kl - 1) + po[2];
        const float ft = floorf(pt), fh = floorf(ph), fw = floorf(pw);
        const float at = pt - ft, ah = ph - fh, aw = pw - fw;
        const int it = (int)ft, ih = (int)fh, iw = (int)fw;
        i32x4 idx[2]; f32x4 wgt[2];
        #pragma unroll
        for (int dt = 0; dt < 2; ++dt)
        #pragma unroll
        for (int dh = 0; dh < 2; ++dh)
        #pragma unroll
        for (int dw = 0; dw < 2; ++dw) {
            const int c = (dt * 2 + dh) * 2 + dw;
            const int ti = it + dt, hi = ih + dh, wi = iw + dw;
            const bool v = (ti >= 0) && (ti < TT) && (hi >= 0) && (hi < HH) && (wi >= 0) && (wi < WW);
            float wv = (dt ? at : 1.f - at) * (dh ? ah : 1.f - ah) * (dw ? aw : 1.f - aw);
            const int tc = min(max(ti, 0), TT - 1), hc = min(max(hi, 0), HH - 1), wc = min(max(wi, 0), WW - 1);
            const int r3 = ((tc + 1) * 26 + (hc + 1)) * 26 + (wc + 1);
            idx[c >> 2][c & 3] = r3 * 512;             // byte offset of row in xbf3
            wgt[c >> 2][c & 3] = v ? wv : 0.f;
        }
        char* rec = &recs[tid * 64];
        *(i32x4*)(rec)      = idx[0];
        *(i32x4*)(rec + 16) = idx[1];
        *(f32x4*)(rec + 32) = wgt[0];
        *(f32x4*)(rec + 48) = wgt[1];
    }
    __syncthreads();

    const int lane = tid & 63, wave = tid >> 6;
    const int half = lane >> 5, lch = lane & 31;       // half-wave owns one n; 8 ch/lane
    const char* xb = (const char*)xbf3 + lch * 16;
    short* Sk = S + (size_t)k * NN * 256 + lch * 8;

    for (int i = 0; i < 16; i += 4) {                  // 4 n per iter (2 per half-wave)
        const int na = wave * 16 + i + half;
        const int nb = na + 2;
        const char* ra = &recs[na * 64];
        const char* rb = &recs[nb * 64];
        const i32x4 ia0 = *(const i32x4*)(ra);
        const i32x4 ia1 = *(const i32x4*)(ra + 16);
        const f32x4 wa0 = *(const f32x4*)(ra + 32);
        const f32x4 wa1 = *(const f32x4*)(ra + 48);
        const i32x4 ib0 = *(const i32x4*)(rb);
        const i32x4 ib1 = *(const i32x4*)(rb + 16);
        const f32x4 wb0 = *(const f32x4*)(rb + 32);
        const f32x4 wb1 = *(const f32x4*)(rb + 48);

        u32x4 ga[8], gb[8];                            // 16 x 16B gathers in flight
        #pragma unroll
        for (int c = 0; c < 4; ++c) {
            ga[c]     = *(const u32x4*)(xb + ia0[c]);
            ga[c + 4] = *(const u32x4*)(xb + ia1[c]);
            gb[c]     = *(const u32x4*)(xb + ib0[c]);
            gb[c + 4] = *(const u32x4*)(xb + ib1[c]);
        }

        float sa[8] = {}, sb[8] = {};
        #pragma unroll
        for (int c = 0; c < 8; ++c) {
            const float va = (c < 4) ? wa0[c & 3] : wa1[c & 3];
            const float vb = (c < 4) ? wb0[c & 3] : wb1[c & 3];
            #pragma unroll
            for (int j = 0; j < 4; ++j) {
                sa[2*j]   = fmaf(va, __uint_as_float(ga[c][j] << 16),         sa[2*j]);
                sa[2*j+1] = fmaf(va, __uint_as_float(ga[c][j] & 0xffff0000u), sa[2*j+1]);
                sb[2*j]   = fmaf(vb, __uint_as_float(gb[c][j] << 16),         sb[2*j]);
                sb[2*j+1] = fmaf(vb, __uint_as_float(gb[c][j] & 0xffff0000u), sb[2*j+1]);
            }
        }
        short8 oa, ob;
        #pragma unroll
        for (int m = 0; m < 8; ++m) { oa[m] = f2bf(sa[m]); ob[m] = f2bf(sb[m]); }
        *(short8*)(Sk + (size_t)(n0 + na) * 256) = oa;
        *(short8*)(Sk + (size_t)(n0 + nb) * 256) = ob;
    }
}

// ---------------------------------------------------------------- conv GEMM
// 128x128 tile, 4 waves (2x2), BK=64, split-K=9 -- now DOUBLE-BUFFERED with
// raw s_barrier + counted vmcnt(8): tile t+1's 8 global_load_lds stay in
// flight under tile t's MFMAs (T4). Math order identical to round 14.
template<int CP>
__global__ __launch_bounds__(256, 2) void gemm_conv_sk(
    const short* __restrict__ src,            // bf16 [N3][256] plain
    const short* __restrict__ wrb_sw,         // bf16 pre-swizzled [y][kt][8192]
    short* __restrict__ P)
{
    __shared__ short Ap[2][8192];             // A [128 rows][64 kk] swizzled, x2
    __shared__ short Bw[2][8192];             // B [128 rows][64 kk] swizzled, x2
    const int tid = threadIdx.x;
    const int l = tid & 63, w = tid >> 6;
    const int n0 = blockIdx.x * 128, co0 = blockIdx.y * 128, split = blockIdx.z;
    const int wr = w >> 1, wc = w & 1;        // wave 2x2 grid
    const int lm = l & 15, lq = l >> 4;
    const int rswz = (lm & 7) << 3;
    const int kt0 = split * KT_PER;

    const int colA = 8 * ((l & 7) ^ ((l >> 3) & 7));
    int r3[4];
    #pragma unroll
    for (int j = 0; j < 4; ++j)
        r3[j] = n3_of(n0 + w * 32 + j * 8 + (l >> 3));
    const short* bbase = wrb_sw + ((size_t)blockIdx.y * KTILES) * 8192 + (w * 4) * 512 + l * 8;

    auto stage = [&](int buf, int kt) {
        const int k = kt >> 2, ci0 = (kt & 3) * 64;
        const int dt = k / 9 - 1, dh = (k % 9) / 3 - 1, dw = k % 3 - 1;
        const int d3 = (dt * 26 + dh) * 26 + dw;
        #pragma unroll
        for (int j = 0; j < 4; ++j)
            gload16(src + (size_t)(r3[j] + d3) * 256 + ci0 + colA, &Ap[buf][(w * 4 + j) * 512]);
        const short* b = bbase + (size_t)kt * 8192;
        #pragma unroll
        for (int j = 0; j < 4; ++j)
            gload16(b + j * 512, &Bw[buf][(w * 4 + j) * 512]);
    };

    f32x4 acc[4][4] = {};
    int cur = 0;
    stage(0, kt0);

    for (int i = 0; i < KT_PER; ++i) {
        if (i + 1 < KT_PER) {
            stage(cur ^ 1, kt0 + i + 1);       // 8 more loads in flight
            // wait only for tile i's 8 loads; tile i+1's ride under the MFMAs
            asm volatile("s_waitcnt vmcnt(8)\n\ts_barrier" ::: "memory");
        } else {
            asm volatile("s_waitcnt vmcnt(0)\n\ts_barrier" ::: "memory");
        }
        #pragma unroll
        for (int ks = 0; ks < 2; ++ks) {
            const int c = (ks * 32 + lq * 8) ^ rswz;
            short8 a[4], bf[4];
            #pragma unroll
            for (int m = 0; m < 4; ++m)
                a[m] = *(const short8*)&Ap[cur][(wr * 64 + m * 16 + lm) * 64 + c];
            #pragma unroll
            for (int nb = 0; nb < 4; ++nb)
                bf[nb] = *(const short8*)&Bw[cur][(wc * 64 + nb * 16 + lm) * 64 + c];
            #pragma unroll
            for (int m = 0; m < 4; ++m)
            #pragma unroll
            for (int nb = 0; nb < 4; ++nb)
                acc[m][nb] = MFMA16(a[m], bf[nb], acc[m][nb], 0, 0, 0);
        }
        asm volatile("s_barrier" ::: "memory");   // all reads of buf[cur] done
        cur ^= 1;
    }
    #pragma unroll
    for (int m = 0; m < 4; ++m)
    #pragma unroll
    for (int nb = 0; nb < 4; ++nb) {
        int co = co0 + wc * 64 + nb * 16 + lm;
        int n = n0 + wr * 64 + m * 16 + lq * 4;
        short4v o;
        #pragma unroll
        for (int j = 0; j < 4; ++j) o[j] = f2bf(acc[m][nb][j]);
        *(short4v*)(P + ((size_t)split * CP + co) * NN + n) = o;
    }
}

// ---------------------------------------------------------------- deform GEMM (same pipeline)
__global__ __launch_bounds__(256, 2) void gemm_deform_sk(
    const short* __restrict__ S,              // bf16 [27][NN][256] plain
    const short* __restrict__ wrb_sw,
    short* __restrict__ P)
{
    __shared__ short Ap[2][8192];
    __shared__ short Bw[2][8192];
    const int tid = threadIdx.x;
    const int l = tid & 63, w = tid >> 6;
    const int n0 = blockIdx.x * 128, co0 = blockIdx.y * 128, split = blockIdx.z;
    const int wr = w >> 1, wc = w & 1;
    const int lm = l & 15, lq = l >> 4;
    const int rswz = (lm & 7) << 3;
    const int kt0 = split * KT_PER;

    const int colA = 8 * ((l & 7) ^ ((l >> 3) & 7));
    int rA[4];
    #pragma unroll
    for (int j = 0; j < 4; ++j)
        rA[j] = n0 + w * 32 + j * 8 + (l >> 3);
    const short* bbase = wrb_sw + ((size_t)blockIdx.y * KTILES) * 8192 + (w * 4) * 512 + l * 8;

    auto stage = [&](int buf, int kt) {
        const int k = kt >> 2, ci0 = (kt & 3) * 64;
        #pragma unroll
        for (int j = 0; j < 4; ++j)
            gload16(S + ((size_t)k * NN + rA[j]) * 256 + ci0 + colA, &Ap[buf][(w * 4 + j) * 512]);
        const short* b = bbase + (size_t)kt * 8192;
        #pragma unroll
        for (int j = 0; j < 4; ++j)
            gload16(b + j * 512, &Bw[buf][(w * 4 + j) * 512]);
    };

    f32x4 acc[4][4] = {};
    int cur = 0;
    stage(0, kt0);

    for (int i = 0; i < KT_PER; ++i) {
        if (i + 1 < KT_PER) {
            stage(cur ^ 1, kt0 + i + 1);
            asm volatile("s_waitcnt vmcnt(8)\n\ts_barrier" ::: "memory");
        } else {
            asm volatile("s_waitcnt vmcnt(0)\n\ts_barrier" ::: "memory");
        }
        #pragma unroll
        for (int ks = 0; ks < 2; ++ks) {
            const int c = (ks * 32 + lq * 8) ^ rswz;
            short8 a[4], bf[4];
            #pragma unroll
            for (int m = 0; m < 4; ++m)
                a[m] = *(const short8*)&Ap[cur][(wr * 64 + m * 16 + lm) * 64 + c];
            #pragma unroll
            for (int nb = 0; nb < 4; ++nb)
                bf[nb] = *(const short8*)&Bw[cur][(wc * 64 + nb * 16 + lm) * 64 + c];
            #pragma unroll
            for (int m = 0; m < 4; ++m)
            #pragma unroll
            for (int nb = 0; nb < 4; ++nb)
                acc[m][nb] = MFMA16(a[m], bf[nb], acc[m][nb], 0, 0, 0);
        }
        asm volatile("s_barrier" ::: "memory");
        cur ^= 1;
    }
    #pragma unroll
    for (int m = 0; m < 4; ++m)
    #pragma unroll
    for (int nb = 0; nb < 4; ++nb) {
        int co = co0 + wc * 64 + nb * 16 + lm;
        int n = n0 + wr * 64 + m * 16 + lq * 4;
        short4v o;
        #pragma unroll
        for (int j = 0; j < 4; ++j) o[j] = f2bf(acc[m][nb][j]);
        *(short4v*)(P + ((size_t)split * 256 + co) * NN + n) = o;
    }
}

// ---------------------------------------------------------------- reduces (bf16 partials -> f32 sum)
template<bool RELU>
__global__ __launch_bounds__(256) void reduce_k(
    const short* __restrict__ P, const float* __restrict__ bias,
    float* __restrict__ dst, int Cout, int CP)
{
    int id = blockIdx.x * 256 + threadIdx.x;
    int total = Cout * (NN / 4);
    if (id >= total) return;
    int co = id / (NN / 4), n4 = id - co * (NN / 4);
    const short* p0 = P + ((size_t)co) * NN + n4 * 4;
    float v[4] = {};
    #pragma unroll
    for (int s = 0; s < NSPLIT; ++s) {
        short4v u = *(const short4v*)(p0 + (size_t)s * CP * NN);
        #pragma unroll
        for (int q = 0; q < 4; ++q) v[q] += bf2f(u[q]);
    }
    float bv = bias[co];
    f32x4 o;
    #pragma unroll
    for (int q = 0; q < 4; ++q) {
        float f = v[q] + bv;
        if (RELU) f = fmaxf(f, 0.f);
        o[q] = f;
    }
    *(f32x4*)(dst + (size_t)co * NN + n4 * 4) = o;
}

// bf16 3D-padded transposed output (h layers): bias+relu+cvt+transpose fused
__global__ __launch_bounds__(256) void reduce_bf3(
    const short* __restrict__ P, const float* __restrict__ bias,
    short* __restrict__ dst)
{
    __shared__ float T[64][65];
    const int lane = threadIdx.x & 63, wave = threadIdx.x >> 6;
    const int n0 = blockIdx.x * 64, co0 = blockIdx.y * 64;
    #pragma unroll
    for (int j = 0; j < 16; ++j) {
        int co_l = wave * 16 + j, co = co0 + co_l;
        const short* p0 = P + (size_t)co * NN + n0 + lane;
        float a = 0.f;
        #pragma unroll
        for (int s = 0; s < NSPLIT; ++s) a += bf2f(p0[(size_t)s * 256 * NN]);
        T[co_l][lane] = fmaxf(a + bias[co], 0.f);
    }
    __syncthreads();
    #pragma unroll
    for (int j = 0; j < 16; ++j) {
        int n_l = wave * 16 + j;
        dst[(size_t)n3_of(n0 + n_l) * 256 + co0 + lane] = f2bf(T[lane][n_l]);
    }
}

// ----------------------------------------------------------------
extern "C" void kernel_launch(void* const* d_in, const int* in_sizes, int n_in,
                              void* d_out, int out_size, void* d_ws, size_t ws_size,
                              hipStream_t stream)
{
    const float* x   = (const float*)d_in[0];
    const float* l1w = (const float*)d_in[1];
    const float* l1b = (const float*)d_in[2];
    const float* l2w = (const float*)d_in[3];
    const float* l2b = (const float*)d_in[4];
    const float* l3w = (const float*)d_in[5];
    const float* l3b = (const float*)d_in[6];
    const float* dfw = (const float*)d_in[7];
    const float* dfb = (const float*)d_in[8];
    const float* c3w = (const float*)d_in[9];
    const float* c3b = (const float*)d_in[10];
    float* out = (float*)d_out;

    // ---- workspace ----
    // Overlay region [0, 63.7MB): S (sample phase) over conv-phase-only buffers.
    char* base = (char*)d_ws;
    short* S    = (short*)base;                              // 27*NN*256*2 = 63,700,992
    short* h1b  = (short*)(base);                            // 3,461,120 each (h2b/h3b follow)
    short* wrb1 = (short*)(base + 10383360);                 // 3,538,944 each
    short* wrb2 = (short*)(base + 13922304);
    short* wrb3 = (short*)(base + 17461248);
    short* wrbd = (short*)(base + 21000192);                 // 1,769,472 (ends 22.77MB < 63.7MB)
    short* h2b  = (short*)(base + 3461120);
    short* h3b  = (short*)(base + 6922240);
    // Non-overlaid region (live across the sample phase):
    char* q = base + 63700992;
    short* xbf3 = (short*)q; q += 3461120;                   // N3*256*2
    short* wrbc = (short*)q; q += 3538944;                   // 256*KDIM*2
    short* P    = (short*)q;                                 // 9*256*NN*2 = 21,233,664

    const dim3 blk(256);
    // one prep launch: 5 repacks + transpose + pad-zeroing
    prep_k<<<dim3(288, 7), blk, 0, stream>>>(x, l1w, l2w, l3w, c3w, dfw,
                                             wrb1, wrb2, wrb3, wrbc, wrbd,
                                             xbf3, h1b);

    const int rg256 = (256 * (NN / 4) + 255) / 256;   // 1152

    gemm_conv_sk<256><<<dim3(36, 2, NSPLIT), blk, 0, stream>>>(xbf3, wrb1, P);
    reduce_bf3       <<<dim3(72, 4),         blk, 0, stream>>>(P, l1b, h1b);
    gemm_conv_sk<256><<<dim3(36, 2, NSPLIT), blk, 0, stream>>>(h1b, wrb2, P);
    reduce_bf3       <<<dim3(72, 4),         blk, 0, stream>>>(P, l2b, h2b);
    gemm_conv_sk<256><<<dim3(36, 2, NSPLIT), blk, 0, stream>>>(h2b, wrb3, P);
    reduce_bf3       <<<dim3(72, 4),         blk, 0, stream>>>(P, l3b, h3b);
    gemm_conv_sk<128><<<dim3(36, 1, NSPLIT), blk, 0, stream>>>(h3b, wrbd, P);

    // offsets-reduce folded into sample_k (reads bf16 partials + dfb directly)
    sample_k<<<dim3(72, 27), blk, 0, stream>>>(xbf3, P, dfb, S);
    gemm_deform_sk<<<dim3(36, 2, NSPLIT), blk, 0, stream>>>(S, wrbc, P);
    reduce_k<false><<<dim3(rg256), blk, 0, stream>>>(P, c3b, out, 256, 256);
}

// Round 17
// 199.144 us; speedup vs baseline: 1.0990x; 1.0990x over previous
//
#include <hip/hip_runtime.h>

#define TT 8
#define HH 24
#define WW 24
#define NN 4608            // T*H*W
#define CIN 256
#define N3 6760            // padded volume 10*26*26 (bf16 transposed layout rows)
#define KDIM 6912          // 27 taps * 256 ci
#define BK 64
#define KTILES 108         // KDIM / BK
#define NSPLIT 9
#define KT_PER 12          // KTILES / NSPLIT

typedef short short8 __attribute__((ext_vector_type(8)));
typedef short short4v __attribute__((ext_vector_type(4)));
typedef float f32x4  __attribute__((ext_vector_type(4)));
typedef int   i32x4  __attribute__((ext_vector_type(4)));
typedef unsigned int u32x4 __attribute__((ext_vector_type(4)));

#define MFMA16 __builtin_amdgcn_mfma_f32_16x16x32_bf16

__device__ __forceinline__ short f2bf(float f) {       // RNE f32 -> bf16 bits
    unsigned u = __float_as_uint(f);
    unsigned r = u + 0x7fffu + ((u >> 16) & 1u);
    return (short)(r >> 16);
}
__device__ __forceinline__ float bf2f(short s) {
    return __uint_as_float(((unsigned)(unsigned short)s) << 16);
}

__device__ __forceinline__ int n3_of(int n) {          // interior n -> padded row
    int t = n / (HH * WW), r = n % (HH * WW), h = r / WW, w = r % WW;
    return ((t + 1) * 26 + (h + 1)) * 26 + (w + 1);
}

// async 16B global -> LDS (wave-uniform LDS base + lane*16; global addr per-lane)
__device__ __forceinline__ void gload16(const void* gsrc, void* lds) {
    __builtin_amdgcn_global_load_lds(
        (const __attribute__((address_space(1))) void*)gsrc,
        (__attribute__((address_space(3))) void*)lds, 16, 0, 0);
}

// Bijective XCD-aware remap (m204): hardware assigns XCD = linear%8; regroup so
// 1/8th-chunks of the LOGICAL (x-fastest) order land on one XCD -> B-panel and
// A-row sharers hit the same per-XCD L2. Works for any grid size.
__device__ __forceinline__ void xcd_remap(int& bx, int& by, int& bz) {
    const int gx = gridDim.x, gy = gridDim.y;
    const int lin = blockIdx.x + gx * (blockIdx.y + gy * blockIdx.z);
    const int total = gx * gy * gridDim.z;
    const int q = total >> 3, r = total & 7;
    const int xcd = lin & 7, idx = lin >> 3;
    const int wg = (xcd < r ? xcd * (q + 1) : r * (q + 1) + (xcd - r) * q) + idx;
    bx = wg % gx;
    const int rest = wg / gx;
    by = rest % gy;
    bz = rest / gy;
}

// ---------------------------------------------------------------- merged prep
// grid (288, 7): sel 0-4 = weight repacks (LDS-staged coalesced), sel 5 =
// x transpose -> xbf3, sel 6 = zero pad rows of xbf3/h1b/h2b/h3b.
__global__ __launch_bounds__(256) void prep_k(
    const float* __restrict__ x,
    const float* __restrict__ w1, const float* __restrict__ w2,
    const float* __restrict__ w3, const float* __restrict__ wc,
    const float* __restrict__ wd,
    short* __restrict__ d1, short* __restrict__ d2,
    short* __restrict__ d3, short* __restrict__ dc, short* __restrict__ dd,
    short* __restrict__ xbf3, short* __restrict__ h1b)
{
    __shared__ char smem[27648];                       // 27KB union
    const int sel = blockIdx.y;

    if (sel < 5) {                                     // ---- weight repack ----
        if (blockIdx.x >= 256) return;
        const int o = blockIdx.x, ci = threadIdx.x;
        const float* w; short* dst; int Cout = 256;
        if      (sel == 0) { w = w1; dst = d1; }
        else if (sel == 1) { w = w2; dst = d2; }
        else if (sel == 2) { w = w3; dst = d3; }
        else if (sel == 3) { w = wc; dst = dc; }
        else               { w = wd; dst = dd; Cout = 81; if (o >= 128) return; }
        float* buf = (float*)smem;                     // one o-row [ci][k]
        if (o < Cout) {                                // coalesced row load
            const float* src = w + (size_t)o * KDIM;
            #pragma unroll
            for (int j = 0; j < 27; ++j)
                buf[j * 256 + ci] = src[j * 256 + ci];
        }
        __syncthreads();
        const int row = o & 127, y = o >> 7;
        #pragma unroll
        for (int k = 0; k < 27; ++k) {
            int K = k * 256 + ci;
            int kt = K >> 6, kk = K & 63;
            int slot = (kk >> 3) ^ (row & 7), e = kk & 7;
            size_t idx = ((size_t)(y * KTILES + kt)) * 8192 + row * 64 + slot * 8 + e;
            float v = (o < Cout) ? buf[ci * 27 + k] : 0.f;
            dst[idx] = f2bf(v);
        }
    } else if (sel == 5) {                             // ---- x transpose ----
        float (*T)[65] = (float(*)[65])smem;
        const int bx = blockIdx.x;                     // 288 = 72 x 4
        const int n0 = (bx % 72) * 64, ci0 = (bx / 72) * 64;
        const int lane = threadIdx.x & 63, wave = threadIdx.x >> 6;
        #pragma unroll
        for (int j = 0; j < 16; ++j) {
            int ci_l = wave * 16 + j;
            T[ci_l][lane] = x[(size_t)(ci0 + ci_l) * NN + n0 + lane];
        }
        __syncthreads();
        #pragma unroll
        for (int j = 0; j < 16; ++j) {
            int n_l = wave * 16 + j;
            xbf3[(size_t)n3_of(n0 + n_l) * 256 + ci0 + lane] = f2bf(T[lane][n_l]);
        }
    } else {                                           // ---- zero pad rows ----
        const int tid = threadIdx.x;
        for (int r = blockIdx.x * 27; r < min((int)(blockIdx.x * 27 + 27), N3); ++r) {
            int t3 = r / 676, rem = r % 676, h3 = rem / 26, w3 = rem % 26;
            bool interior = (t3 >= 1 && t3 <= 8 && h3 >= 1 && h3 <= 24 && w3 >= 1 && w3 <= 24);
            if (!interior && tid < 128) {
                ((unsigned*)(xbf3 + (size_t)r * 256))[tid] = 0;
                ((unsigned*)(h1b  + (size_t)r * 256))[tid] = 0;
                ((unsigned*)(h1b + 1730560 + (size_t)r * 256))[tid] = 0;   // h2b
                ((unsigned*)(h1b + 3461120 + (size_t)r * 256))[tid] = 0;   // h3b
            }
        }
    }
}

// ---------------------------------------------------------------- sampler
// S[k][n][ci] = bf16( sum_c w_c * xbf3[row_c][ci] ).
// Offsets-reduce folded in: records built from bf16 partials Poff (+ bias).
__global__ __launch_bounds__(256) void sample_k(
    const short* __restrict__ xbf3, const short* __restrict__ Poff,
    const float* __restrict__ dfb, short* __restrict__ S)
{
    __shared__ char recs[64 * 64];                     // 64 records x 64B
    const int k = blockIdx.y, n0 = blockIdx.x * 64;
    const int tid = threadIdx.x;

    if (tid < 64) {                                    // compute this block's records
        const int n = n0 + tid;
        const int t = n / (HH * WW), r = n % (HH * WW), h = r / WW, w2 = r % WW;
        const int ki = k / 9, kj = (k % 9) / 3, kl = k % 3;
        float po[3];
        #pragma unroll
        for (int d = 0; d < 3; ++d) {
            const int ch = k * 3 + d;
            float a = 0.f;
            #pragma unroll
            for (int s = 0; s < NSPLIT; ++s)
                a += bf2f(Poff[((size_t)(s * 128 + ch)) * NN + n]);
            po[d] = a + dfb[ch];
        }
        const float pt = (float)(t  + ki - 1) + po[0];
        const float ph = (float)(h  + kj - 1) + po[1];
        const float pw = (float)(w2 + kl - 1) + po[2];
        const float ft = floorf(pt), fh = floorf(ph), fw = floorf(pw);
        const float at = pt - ft, ah = ph - fh, aw = pw - fw;
        const int it = (int)ft, ih = (int)fh, iw = (int)fw;
        i32x4 idx[2]; f32x4 wgt[2];
        #pragma unroll
        for (int dt = 0; dt < 2; ++dt)
        #pragma unroll
        for (int dh = 0; dh < 2; ++dh)
        #pragma unroll
        for (int dw = 0; dw < 2; ++dw) {
            const int c = (dt * 2 + dh) * 2 + dw;
            const int ti = it + dt, hi = ih + dh, wi = iw + dw;
            const bool v = (ti >= 0) && (ti < TT) && (hi >= 0) && (hi < HH) && (wi >= 0) && (wi < WW);
            float wv = (dt ? at : 1.f - at) * (dh ? ah : 1.f - ah) * (dw ? aw : 1.f - aw);
            const int tc = min(max(ti, 0), TT - 1), hc = min(max(hi, 0), HH - 1), wc = min(max(wi, 0), WW - 1);
            const int r3 = ((tc + 1) * 26 + (hc + 1)) * 26 + (wc + 1);
            idx[c >> 2][c & 3] = r3 * 512;             // byte offset of row in xbf3
            wgt[c >> 2][c & 3] = v ? wv : 0.f;
        }
        char* rec = &recs[tid * 64];
        *(i32x4*)(rec)      = idx[0];
        *(i32x4*)(rec + 16) = idx[1];
        *(f32x4*)(rec + 32) = wgt[0];
        *(f32x4*)(rec + 48) = wgt[1];
    }
    __syncthreads();

    const int lane = tid & 63, wave = tid >> 6;
    const int half = lane >> 5, lch = lane & 31;       // half-wave owns one n; 8 ch/lane
    const char* xb = (const char*)xbf3 + lch * 16;
    short* Sk = S + (size_t)k * NN * 256 + lch * 8;

    for (int i = 0; i < 16; i += 4) {                  // 4 n per iter (2 per half-wave)
        const int na = wave * 16 + i + half;
        const int nb = na + 2;
        const char* ra = &recs[na * 64];
        const char* rb = &recs[nb * 64];
        const i32x4 ia0 = *(const i32x4*)(ra);
        const i32x4 ia1 = *(const i32x4*)(ra + 16);
        const f32x4 wa0 = *(const f32x4*)(ra + 32);
        const f32x4 wa1 = *(const f32x4*)(ra + 48);
        const i32x4 ib0 = *(const i32x4*)(rb);
        const i32x4 ib1 = *(const i32x4*)(rb + 16);
        const f32x4 wb0 = *(const f32x4*)(rb + 32);
        const f32x4 wb1 = *(const f32x4*)(rb + 48);

        u32x4 ga[8], gb[8];                            // 16 x 16B gathers in flight
        #pragma unroll
        for (int c = 0; c < 4; ++c) {
            ga[c]     = *(const u32x4*)(xb + ia0[c]);
            ga[c + 4] = *(const u32x4*)(xb + ia1[c]);
            gb[c]     = *(const u32x4*)(xb + ib0[c]);
            gb[c + 4] = *(const u32x4*)(xb + ib1[c]);
        }

        float sa[8] = {}, sb[8] = {};
        #pragma unroll
        for (int c = 0; c < 8; ++c) {
            const float va = (c < 4) ? wa0[c & 3] : wa1[c & 3];
            const float vb = (c < 4) ? wb0[c & 3] : wb1[c & 3];
            #pragma unroll
            for (int j = 0; j < 4; ++j) {
                sa[2*j]   = fmaf(va, __uint_as_float(ga[c][j] << 16),         sa[2*j]);
                sa[2*j+1] = fmaf(va, __uint_as_float(ga[c][j] & 0xffff0000u), sa[2*j+1]);
                sb[2*j]   = fmaf(vb, __uint_as_float(gb[c][j] << 16),         sb[2*j]);
                sb[2*j+1] = fmaf(vb, __uint_as_float(gb[c][j] & 0xffff0000u), sb[2*j+1]);
            }
        }
        short8 oa, ob;
        #pragma unroll
        for (int m = 0; m < 8; ++m) { oa[m] = f2bf(sa[m]); ob[m] = f2bf(sb[m]); }
        *(short8*)(Sk + (size_t)(n0 + na) * 256) = oa;
        *(short8*)(Sk + (size_t)(n0 + nb) * 256) = ob;
    }
}

// ---------------------------------------------------------------- conv GEMM
// Round-14 structure (known-good): 128x128 tile, 4 waves (2x2), BK=64,
// single-buffered 32KB LDS, 2 barriers/K-tile, split-K=9, 3 blocks/CU.
// + XCD-aware bijective block remap (T1).
template<int CP>
__global__ __launch_bounds__(256, 3) void gemm_conv_sk(
    const short* __restrict__ src,            // bf16 [N3][256] plain
    const short* __restrict__ wrb_sw,         // bf16 pre-swizzled [y][kt][8192]
    short* __restrict__ P)
{
    __shared__ short Ap[8192];                // A [128 rows][64 kk] swizzled
    __shared__ short Bw[8192];                // B [128 rows][64 kk] swizzled
    int bx, by, bz;
    xcd_remap(bx, by, bz);
    const int tid = threadIdx.x;
    const int l = tid & 63, w = tid >> 6;
    const int n0 = bx * 128, co0 = by * 128, split = bz;
    const int wr = w >> 1, wc = w & 1;        // wave 2x2 grid
    const int lm = l & 15, lq = l >> 4;
    const int rswz = (lm & 7) << 3;
    const int kt0 = split * KT_PER;

    const int colA = 8 * ((l & 7) ^ ((l >> 3) & 7));
    int r3[4];
    #pragma unroll
    for (int j = 0; j < 4; ++j)
        r3[j] = n3_of(n0 + w * 32 + j * 8 + (l >> 3));
    const short* bbase = wrb_sw + ((size_t)by * KTILES) * 8192 + (w * 4) * 512 + l * 8;

    f32x4 acc[4][4] = {};

    for (int i = 0; i < KT_PER; ++i) {
        const int kt = kt0 + i;
        const int k = kt >> 2, ci0 = (kt & 3) * 64;
        const int dt = k / 9 - 1, dh = (k % 9) / 3 - 1, dw = k % 3 - 1;
        const int d3 = (dt * 26 + dh) * 26 + dw;
        #pragma unroll
        for (int j = 0; j < 4; ++j)
            gload16(src + (size_t)(r3[j] + d3) * 256 + ci0 + colA, &Ap[(w * 4 + j) * 512]);
        const short* b = bbase + (size_t)kt * 8192;
        #pragma unroll
        for (int j = 0; j < 4; ++j)
            gload16(b + j * 512, &Bw[(w * 4 + j) * 512]);
        __syncthreads();                       // drains vmcnt(0): tile staged
        #pragma unroll
        for (int ks = 0; ks < 2; ++ks) {
            const int c = (ks * 32 + lq * 8) ^ rswz;
            short8 a[4], bf[4];
            #pragma unroll
            for (int m = 0; m < 4; ++m)
                a[m] = *(const short8*)&Ap[(wr * 64 + m * 16 + lm) * 64 + c];
            #pragma unroll
            for (int nb = 0; nb < 4; ++nb)
                bf[nb] = *(const short8*)&Bw[(wc * 64 + nb * 16 + lm) * 64 + c];
            #pragma unroll
            for (int m = 0; m < 4; ++m)
            #pragma unroll
            for (int nb = 0; nb < 4; ++nb)
                acc[m][nb] = MFMA16(a[m], bf[nb], acc[m][nb], 0, 0, 0);
        }
        __syncthreads();                       // all reads done before next stage
    }
    #pragma unroll
    for (int m = 0; m < 4; ++m)
    #pragma unroll
    for (int nb = 0; nb < 4; ++nb) {
        int co = co0 + wc * 64 + nb * 16 + lm;
        int n = n0 + wr * 64 + m * 16 + lq * 4;
        short4v o;
        #pragma unroll
        for (int j = 0; j < 4; ++j) o[j] = f2bf(acc[m][nb][j]);
        *(short4v*)(P + ((size_t)split * CP + co) * NN + n) = o;
    }
}

// ---------------------------------------------------------------- deform GEMM (same structure)
__global__ __launch_bounds__(256, 3) void gemm_deform_sk(
    const short* __restrict__ S,              // bf16 [27][NN][256] plain
    const short* __restrict__ wrb_sw,
    short* __restrict__ P)
{
    __shared__ short Ap[8192];
    __shared__ short Bw[8192];
    int bx, by, bz;
    xcd_remap(bx, by, bz);
    const int tid = threadIdx.x;
    const int l = tid & 63, w = tid >> 6;
    const int n0 = bx * 128, co0 = by * 128, split = bz;
    const int wr = w >> 1, wc = w & 1;
    const int lm = l & 15, lq = l >> 4;
    const int rswz = (lm & 7) << 3;
    const int kt0 = split * KT_PER;

    const int colA = 8 * ((l & 7) ^ ((l >> 3) & 7));
    int rA[4];
    #pragma unroll
    for (int j = 0; j < 4; ++j)
        rA[j] = n0 + w * 32 + j * 8 + (l >> 3);
    const short* bbase = wrb_sw + ((size_t)by * KTILES) * 8192 + (w * 4) * 512 + l * 8;

    f32x4 acc[4][4] = {};

    for (int i = 0; i < KT_PER; ++i) {
        const int kt = kt0 + i;
        const int k = kt >> 2, ci0 = (kt & 3) * 64;
        #pragma unroll
        for (int j = 0; j < 4; ++j)
            gload16(S + ((size_t)k * NN + rA[j]) * 256 + ci0 + colA, &Ap[(w * 4 + j) * 512]);
        const short* b = bbase + (size_t)kt * 8192;
        #pragma unroll
        for (int j = 0; j < 4; ++j)
            gload16(b + j * 512, &Bw[(w * 4 + j) * 512]);
        __syncthreads();
        #pragma unroll
        for (int ks = 0; ks < 2; ++ks) {
            const int c = (ks * 32 + lq * 8) ^ rswz;
            short8 a[4], bf[4];
            #pragma unroll
            for (int m = 0; m < 4; ++m)
                a[m] = *(const short8*)&Ap[(wr * 64 + m * 16 + lm) * 64 + c];
            #pragma unroll
            for (int nb = 0; nb < 4; ++nb)
                bf[nb] = *(const short8*)&Bw[(wc * 64 + nb * 16 + lm) * 64 + c];
            #pragma unroll
            for (int m = 0; m < 4; ++m)
            #pragma unroll
            for (int nb = 0; nb < 4; ++nb)
                acc[m][nb] = MFMA16(a[m], bf[nb], acc[m][nb], 0, 0, 0);
        }
        __syncthreads();
    }
    #pragma unroll
    for (int m = 0; m < 4; ++m)
    #pragma unroll
    for (int nb = 0; nb < 4; ++nb) {
        int co = co0 + wc * 64 + nb * 16 + lm;
        int n = n0 + wr * 64 + m * 16 + lq * 4;
        short4v o;
        #pragma unroll
        for (int j = 0; j < 4; ++j) o[j] = f2bf(acc[m][nb][j]);
        *(short4v*)(P + ((size_t)split * 256 + co) * NN + n) = o;
    }
}

// ---------------------------------------------------------------- reduces (bf16 partials -> f32 sum)
template<bool RELU>
__global__ __launch_bounds__(256) void reduce_k(
    const short* __restrict__ P, const float* __restrict__ bias,
    float* __restrict__ dst, int Cout, int CP)
{
    int id = blockIdx.x * 256 + threadIdx.x;
    int total = Cout * (NN / 4);
    if (id >= total) return;
    int co = id / (NN / 4), n4 = id - co * (NN / 4);
    const short* p0 = P + ((size_t)co) * NN + n4 * 4;
    float v[4] = {};
    #pragma unroll
    for (int s = 0; s < NSPLIT; ++s) {
        short4v u = *(const short4v*)(p0 + (size_t)s * CP * NN);
        #pragma unroll
        for (int q = 0; q < 4; ++q) v[q] += bf2f(u[q]);
    }
    float bv = bias[co];
    f32x4 o;
    #pragma unroll
    for (int q = 0; q < 4; ++q) {
        float f = v[q] + bv;
        if (RELU) f = fmaxf(f, 0.f);
        o[q] = f;
    }
    *(f32x4*)(dst + (size_t)co * NN + n4 * 4) = o;
}

// bf16 3D-padded transposed output (h layers): bias+relu+cvt+transpose fused
__global__ __launch_bounds__(256) void reduce_bf3(
    const short* __restrict__ P, const float* __restrict__ bias,
    short* __restrict__ dst)
{
    __shared__ float T[64][65];
    const int lane = threadIdx.x & 63, wave = threadIdx.x >> 6;
    const int n0 = blockIdx.x * 64, co0 = blockIdx.y * 64;
    #pragma unroll
    for (int j = 0; j < 16; ++j) {
        int co_l = wave * 16 + j, co = co0 + co_l;
        const short* p0 = P + (size_t)co * NN + n0 + lane;
        float a = 0.f;
        #pragma unroll
        for (int s = 0; s < NSPLIT; ++s) a += bf2f(p0[(size_t)s * 256 * NN]);
        T[co_l][lane] = fmaxf(a + bias[co], 0.f);
    }
    __syncthreads();
    #pragma unroll
    for (int j = 0; j < 16; ++j) {
        int n_l = wave * 16 + j;
        dst[(size_t)n3_of(n0 + n_l) * 256 + co0 + lane] = f2bf(T[lane][n_l]);
    }
}

// ----------------------------------------------------------------
extern "C" void kernel_launch(void* const* d_in, const int* in_sizes, int n_in,
                              void* d_out, int out_size, void* d_ws, size_t ws_size,
                              hipStream_t stream)
{
    const float* x   = (const float*)d_in[0];
    const float* l1w = (const float*)d_in[1];
    const float* l1b = (const float*)d_in[2];
    const float* l2w = (const float*)d_in[3];
    const float* l2b = (const float*)d_in[4];
    const float* l3w = (const float*)d_in[5];
    const float* l3b = (const float*)d_in[6];
    const float* dfw = (const float*)d_in[7];
    const float* dfb = (const float*)d_in[8];
    const float* c3w = (const float*)d_in[9];
    const float* c3b = (const float*)d_in[10];
    float* out = (float*)d_out;

    // ---- workspace ----
    // Overlay region [0, 63.7MB): S (sample phase) over conv-phase-only buffers.
    char* base = (char*)d_ws;
    short* S    = (short*)base;                              // 27*NN*256*2 = 63,700,992
    short* h1b  = (short*)(base);                            // 3,461,120 each (h2b/h3b follow)
    short* wrb1 = (short*)(base + 10383360);                 // 3,538,944 each
    short* wrb2 = (short*)(base + 13922304);
    short* wrb3 = (short*)(base + 17461248);
    short* wrbd = (short*)(base + 21000192);                 // 1,769,472 (ends 22.77MB < 63.7MB)
    short* h2b  = (short*)(base + 3461120);
    short* h3b  = (short*)(base + 6922240);
    // Non-overlaid region (live across the sample phase):
    char* q = base + 63700992;
    short* xbf3 = (short*)q; q += 3461120;                   // N3*256*2
    short* wrbc = (short*)q; q += 3538944;                   // 256*KDIM*2
    short* P    = (short*)q;                                 // 9*256*NN*2 = 21,233,664

    const dim3 blk(256);
    // one prep launch: 5 repacks + transpose + pad-zeroing
    prep_k<<<dim3(288, 7), blk, 0, stream>>>(x, l1w, l2w, l3w, c3w, dfw,
                                             wrb1, wrb2, wrb3, wrbc, wrbd,
                                             xbf3, h1b);

    const int rg256 = (256 * (NN / 4) + 255) / 256;   // 1152

    gemm_conv_sk<256><<<dim3(36, 2, NSPLIT), blk, 0, stream>>>(xbf3, wrb1, P);
    reduce_bf3       <<<dim3(72, 4),         blk, 0, stream>>>(P, l1b, h1b);
    gemm_conv_sk<256><<<dim3(36, 2, NSPLIT), blk, 0, stream>>>(h1b, wrb2, P);
    reduce_bf3       <<<dim3(72, 4),         blk, 0, stream>>>(P, l2b, h2b);
    gemm_conv_sk<256><<<dim3(36, 2, NSPLIT), blk, 0, stream>>>(h2b, wrb3, P);
    reduce_bf3       <<<dim3(72, 4),         blk, 0, stream>>>(P, l3b, h3b);
    gemm_conv_sk<128><<<dim3(36, 1, NSPLIT), blk, 0, stream>>>(h3b, wrbd, P);

    // offsets-reduce folded into sample_k (reads bf16 partials + dfb directly)
    sample_k<<<dim3(72, 27), blk, 0, stream>>>(xbf3, P, dfb, S);
    gemm_deform_sk<<<dim3(36, 2, NSPLIT), blk, 0, stream>>>(S, wrbc, P);
    reduce_k<false><<<dim3(rg256), blk, 0, stream>>>(P, c3b, out, 256, 256);
}

// Round 18
// 195.405 us; speedup vs baseline: 1.1200x; 1.0191x over previous
//
#include <hip/hip_runtime.h>

#define TT 8
#define HH 24
#define WW 24
#define NN 4608            // T*H*W
#define CIN 256
#define N3 6760            // padded volume 10*26*26 (bf16 transposed layout rows)
#define KDIM 6912          // 27 taps * 256 ci
#define BK 64
#define KTILES 108         // KDIM / BK
#define NSPLIT 9
#define KT_PER 12          // KTILES / NSPLIT

typedef short short8 __attribute__((ext_vector_type(8)));
typedef short short4v __attribute__((ext_vector_type(4)));
typedef float f32x4  __attribute__((ext_vector_type(4)));
typedef int   i32x4  __attribute__((ext_vector_type(4)));
typedef unsigned int u32x4 __attribute__((ext_vector_type(4)));

#define MFMA16 __builtin_amdgcn_mfma_f32_16x16x32_bf16

__device__ __forceinline__ short f2bf(float f) {       // RNE f32 -> bf16 bits
    unsigned u = __float_as_uint(f);
    unsigned r = u + 0x7fffu + ((u >> 16) & 1u);
    return (short)(r >> 16);
}
__device__ __forceinline__ float bf2f(short s) {
    return __uint_as_float(((unsigned)(unsigned short)s) << 16);
}

__device__ __forceinline__ int n3_of(int n) {          // interior n -> padded row
    int t = n / (HH * WW), r = n % (HH * WW), h = r / WW, w = r % WW;
    return ((t + 1) * 26 + (h + 1)) * 26 + (w + 1);
}

// async 16B global -> LDS (wave-uniform LDS base + lane*16; global addr per-lane)
__device__ __forceinline__ void gload16(const void* gsrc, void* lds) {
    __builtin_amdgcn_global_load_lds(
        (const __attribute__((address_space(1))) void*)gsrc,
        (__attribute__((address_space(3))) void*)lds, 16, 0, 0);
}

// ---------------------------------------------------------------- merged prep
// grid (288, 7): sel 0-4 = weight repacks (LDS-staged coalesced), sel 5 =
// x transpose -> xbf3, sel 6 = zero pad rows of xbf3/h1b/h2b/h3b.
__global__ __launch_bounds__(256) void prep_k(
    const float* __restrict__ x,
    const float* __restrict__ w1, const float* __restrict__ w2,
    const float* __restrict__ w3, const float* __restrict__ wc,
    const float* __restrict__ wd,
    short* __restrict__ d1, short* __restrict__ d2,
    short* __restrict__ d3, short* __restrict__ dc, short* __restrict__ dd,
    short* __restrict__ xbf3, short* __restrict__ h1b)
{
    __shared__ char smem[27648];                       // 27KB union
    const int sel = blockIdx.y;

    if (sel < 5) {                                     // ---- weight repack ----
        if (blockIdx.x >= 256) return;
        const int o = blockIdx.x, ci = threadIdx.x;
        const float* w; short* dst; int Cout = 256;
        if      (sel == 0) { w = w1; dst = d1; }
        else if (sel == 1) { w = w2; dst = d2; }
        else if (sel == 2) { w = w3; dst = d3; }
        else if (sel == 3) { w = wc; dst = dc; }
        else               { w = wd; dst = dd; Cout = 81; if (o >= 128) return; }
        float* buf = (float*)smem;                     // one o-row [ci][k]
        if (o < Cout) {                                // coalesced row load
            const float* src = w + (size_t)o * KDIM;
            #pragma unroll
            for (int j = 0; j < 27; ++j)
                buf[j * 256 + ci] = src[j * 256 + ci];
        }
        __syncthreads();
        const int row = o & 127, y = o >> 7;
        #pragma unroll
        for (int k = 0; k < 27; ++k) {
            int K = k * 256 + ci;
            int kt = K >> 6, kk = K & 63;
            int slot = (kk >> 3) ^ (row & 7), e = kk & 7;
            size_t idx = ((size_t)(y * KTILES + kt)) * 8192 + row * 64 + slot * 8 + e;
            float v = (o < Cout) ? buf[ci * 27 + k] : 0.f;
            dst[idx] = f2bf(v);
        }
    } else if (sel == 5) {                             // ---- x transpose ----
        float (*T)[65] = (float(*)[65])smem;
        const int bx = blockIdx.x;                     // 288 = 72 x 4
        const int n0 = (bx % 72) * 64, ci0 = (bx / 72) * 64;
        const int lane = threadIdx.x & 63, wave = threadIdx.x >> 6;
        #pragma unroll
        for (int j = 0; j < 16; ++j) {
            int ci_l = wave * 16 + j;
            T[ci_l][lane] = x[(size_t)(ci0 + ci_l) * NN + n0 + lane];
        }
        __syncthreads();
        #pragma unroll
        for (int j = 0; j < 16; ++j) {
            int n_l = wave * 16 + j;
            xbf3[(size_t)n3_of(n0 + n_l) * 256 + ci0 + lane] = f2bf(T[lane][n_l]);
        }
    } else {                                           // ---- zero pad rows ----
        const int tid = threadIdx.x;
        for (int r = blockIdx.x * 27; r < min((int)(blockIdx.x * 27 + 27), N3); ++r) {
            int t3 = r / 676, rem = r % 676, h3 = rem / 26, w3 = rem % 26;
            bool interior = (t3 >= 1 && t3 <= 8 && h3 >= 1 && h3 <= 24 && w3 >= 1 && w3 <= 24);
            if (!interior && tid < 128) {
                ((unsigned*)(xbf3 + (size_t)r * 256))[tid] = 0;
                ((unsigned*)(h1b  + (size_t)r * 256))[tid] = 0;
                ((unsigned*)(h1b + 1730560 + (size_t)r * 256))[tid] = 0;   // h2b
                ((unsigned*)(h1b + 3461120 + (size_t)r * 256))[tid] = 0;   // h3b
            }
        }
    }
}

// ---------------------------------------------------------------- sampler
// S[k][n][ci] = bf16( sum_c w_c * xbf3[row_c][ci] ).
// Offsets-reduce folded in: records built from bf16 partials Poff (+ bias).
__global__ __launch_bounds__(256) void sample_k(
    const short* __restrict__ xbf3, const short* __restrict__ Poff,
    const float* __restrict__ dfb, short* __restrict__ S)
{
    __shared__ char recs[64 * 64];                     // 64 records x 64B
    const int k = blockIdx.y, n0 = blockIdx.x * 64;
    const int tid = threadIdx.x;

    if (tid < 64) {                                    // compute this block's records
        const int n = n0 + tid;
        const int t = n / (HH * WW), r = n % (HH * WW), h = r / WW, w2 = r % WW;
        const int ki = k / 9, kj = (k % 9) / 3, kl = k % 3;
        float po[3];
        #pragma unroll
        for (int d = 0; d < 3; ++d) {
            const int ch = k * 3 + d;
            float a = 0.f;
            #pragma unroll
            for (int s = 0; s < NSPLIT; ++s)
                a += bf2f(Poff[((size_t)(s * 128 + ch)) * NN + n]);
            po[d] = a + dfb[ch];
        }
        const float pt = (float)(t  + ki - 1) + po[0];
        const float ph = (float)(h  + kj - 1) + po[1];
        const float pw = (float)(w2 + kl - 1) + po[2];
        const float ft = floorf(pt), fh = floorf(ph), fw = floorf(pw);
        const float at = pt - ft, ah = ph - fh, aw = pw - fw;
        const int it = (int)ft, ih = (int)fh, iw = (int)fw;
        i32x4 idx[2]; f32x4 wgt[2];
        #pragma unroll
        for (int dt = 0; dt < 2; ++dt)
        #pragma unroll
        for (int dh = 0; dh < 2; ++dh)
        #pragma unroll
        for (int dw = 0; dw < 2; ++dw) {
            const int c = (dt * 2 + dh) * 2 + dw;
            const int ti = it + dt, hi = ih + dh, wi = iw + dw;
            const bool v = (ti >= 0) && (ti < TT) && (hi >= 0) && (hi < HH) && (wi >= 0) && (wi < WW);
            float wv = (dt ? at : 1.f - at) * (dh ? ah : 1.f - ah) * (dw ? aw : 1.f - aw);
            const int tc = min(max(ti, 0), TT - 1), hc = min(max(hi, 0), HH - 1), wc = min(max(wi, 0), WW - 1);
            const int r3 = ((tc + 1) * 26 + (hc + 1)) * 26 + (wc + 1);
            idx[c >> 2][c & 3] = r3 * 512;             // byte offset of row in xbf3
            wgt[c >> 2][c & 3] = v ? wv : 0.f;
        }
        char* rec = &recs[tid * 64];
        *(i32x4*)(rec)      = idx[0];
        *(i32x4*)(rec + 16) = idx[1];
        *(f32x4*)(rec + 32) = wgt[0];
        *(f32x4*)(rec + 48) = wgt[1];
    }
    __syncthreads();

    const int lane = tid & 63, wave = tid >> 6;
    const int half = lane >> 5, lch = lane & 31;       // half-wave owns one n; 8 ch/lane
    const char* xb = (const char*)xbf3 + lch * 16;
    short* Sk = S + (size_t)k * NN * 256 + lch * 8;

    for (int i = 0; i < 16; i += 4) {                  // 4 n per iter (2 per half-wave)
        const int na = wave * 16 + i + half;
        const int nb = na + 2;
        const char* ra = &recs[na * 64];
        const char* rb = &recs[nb * 64];
        const i32x4 ia0 = *(const i32x4*)(ra);
        const i32x4 ia1 = *(const i32x4*)(ra + 16);
        const f32x4 wa0 = *(const f32x4*)(ra + 32);
        const f32x4 wa1 = *(const f32x4*)(ra + 48);
        const i32x4 ib0 = *(const i32x4*)(rb);
        const i32x4 ib1 = *(const i32x4*)(rb + 16);
        const f32x4 wb0 = *(const f32x4*)(rb + 32);
        const f32x4 wb1 = *(const f32x4*)(rb + 48);

        u32x4 ga[8], gb[8];                            // 16 x 16B gathers in flight
        #pragma unroll
        for (int c = 0; c < 4; ++c) {
            ga[c]     = *(const u32x4*)(xb + ia0[c]);
            ga[c + 4] = *(const u32x4*)(xb + ia1[c]);
            gb[c]     = *(const u32x4*)(xb + ib0[c]);
            gb[c + 4] = *(const u32x4*)(xb + ib1[c]);
        }

        float sa[8] = {}, sb[8] = {};
        #pragma unroll
        for (int c = 0; c < 8; ++c) {
            const float va = (c < 4) ? wa0[c & 3] : wa1[c & 3];
            const float vb = (c < 4) ? wb0[c & 3] : wb1[c & 3];
            #pragma unroll
            for (int j = 0; j < 4; ++j) {
                sa[2*j]   = fmaf(va, __uint_as_float(ga[c][j] << 16),         sa[2*j]);
                sa[2*j+1] = fmaf(va, __uint_as_float(ga[c][j] & 0xffff0000u), sa[2*j+1]);
                sb[2*j]   = fmaf(vb, __uint_as_float(gb[c][j] << 16),         sb[2*j]);
                sb[2*j+1] = fmaf(vb, __uint_as_float(gb[c][j] & 0xffff0000u), sb[2*j+1]);
            }
        }
        short8 oa, ob;
        #pragma unroll
        for (int m = 0; m < 8; ++m) { oa[m] = f2bf(sa[m]); ob[m] = f2bf(sb[m]); }
        *(short8*)(Sk + (size_t)(n0 + na) * 256) = oa;
        *(short8*)(Sk + (size_t)(n0 + nb) * 256) = ob;
    }
}

// ---------------------------------------------------------------- conv GEMM
// m97 geometry: 128x128 tile, 4 waves (2x2), 64x64 per wave (4x4 frags),
// BK=64, single-buffered LDS (32KB), 2 barriers/K-tile, split-K=9.
// Partials stored as bf16 (f32 AGPR accum, RNE once at store).
template<int CP>
__global__ __launch_bounds__(256, 3) void gemm_conv_sk(
    const short* __restrict__ src,            // bf16 [N3][256] plain
    const short* __restrict__ wrb_sw,         // bf16 pre-swizzled [y][kt][8192]
    short* __restrict__ P)
{
    __shared__ short Ap[8192];                // A [128 rows][64 kk] swizzled
    __shared__ short Bw[8192];                // B [128 rows][64 kk] swizzled
    const int tid = threadIdx.x;
    const int l = tid & 63, w = tid >> 6;
    const int n0 = blockIdx.x * 128, co0 = blockIdx.y * 128, split = blockIdx.z;
    const int wr = w >> 1, wc = w & 1;        // wave 2x2 grid
    const int lm = l & 15, lq = l >> 4;
    const int rswz = (lm & 7) << 3;
    const int kt0 = split * KT_PER;

    const int colA = 8 * ((l & 7) ^ ((l >> 3) & 7));
    int r3[4];
    #pragma unroll
    for (int j = 0; j < 4; ++j)
        r3[j] = n3_of(n0 + w * 32 + j * 8 + (l >> 3));
    const short* bbase = wrb_sw + ((size_t)blockIdx.y * KTILES) * 8192 + (w * 4) * 512 + l * 8;

    f32x4 acc[4][4] = {};

    for (int i = 0; i < KT_PER; ++i) {
        const int kt = kt0 + i;
        const int k = kt >> 2, ci0 = (kt & 3) * 64;
        const int dt = k / 9 - 1, dh = (k % 9) / 3 - 1, dw = k % 3 - 1;
        const int d3 = (dt * 26 + dh) * 26 + dw;
        #pragma unroll
        for (int j = 0; j < 4; ++j)
            gload16(src + (size_t)(r3[j] + d3) * 256 + ci0 + colA, &Ap[(w * 4 + j) * 512]);
        const short* b = bbase + (size_t)kt * 8192;
        #pragma unroll
        for (int j = 0; j < 4; ++j)
            gload16(b + j * 512, &Bw[(w * 4 + j) * 512]);
        __syncthreads();                       // drains vmcnt(0): tile staged
        #pragma unroll
        for (int ks = 0; ks < 2; ++ks) {
            const int c = (ks * 32 + lq * 8) ^ rswz;
            short8 a[4], bf[4];
            #pragma unroll
            for (int m = 0; m < 4; ++m)
                a[m] = *(const short8*)&Ap[(wr * 64 + m * 16 + lm) * 64 + c];
            #pragma unroll
            for (int nb = 0; nb < 4; ++nb)
                bf[nb] = *(const short8*)&Bw[(wc * 64 + nb * 16 + lm) * 64 + c];
            #pragma unroll
            for (int m = 0; m < 4; ++m)
            #pragma unroll
            for (int nb = 0; nb < 4; ++nb)
                acc[m][nb] = MFMA16(a[m], bf[nb], acc[m][nb], 0, 0, 0);
        }
        __syncthreads();                       // all reads done before next stage
    }
    #pragma unroll
    for (int m = 0; m < 4; ++m)
    #pragma unroll
    for (int nb = 0; nb < 4; ++nb) {
        int co = co0 + wc * 64 + nb * 16 + lm;
        int n = n0 + wr * 64 + m * 16 + lq * 4;
        short4v o;
        #pragma unroll
        for (int j = 0; j < 4; ++j) o[j] = f2bf(acc[m][nb][j]);
        *(short4v*)(P + ((size_t)split * CP + co) * NN + n) = o;
    }
}

// ---------------------------------------------------------------- deform GEMM (same geometry)
__global__ __launch_bounds__(256, 3) void gemm_deform_sk(
    const short* __restrict__ S,              // bf16 [27][NN][256] plain
    const short* __restrict__ wrb_sw,
    short* __restrict__ P)
{
    __shared__ short Ap[8192];
    __shared__ short Bw[8192];
    const int tid = threadIdx.x;
    const int l = tid & 63, w = tid >> 6;
    const int n0 = blockIdx.x * 128, co0 = blockIdx.y * 128, split = blockIdx.z;
    const int wr = w >> 1, wc = w & 1;
    const int lm = l & 15, lq = l >> 4;
    const int rswz = (lm & 7) << 3;
    const int kt0 = split * KT_PER;

    const int colA = 8 * ((l & 7) ^ ((l >> 3) & 7));
    int rA[4];
    #pragma unroll
    for (int j = 0; j < 4; ++j)
        rA[j] = n0 + w * 32 + j * 8 + (l >> 3);
    const short* bbase = wrb_sw + ((size_t)blockIdx.y * KTILES) * 8192 + (w * 4) * 512 + l * 8;

    f32x4 acc[4][4] = {};

    for (int i = 0; i < KT_PER; ++i) {
        const int kt = kt0 + i;
        const int k = kt >> 2, ci0 = (kt & 3) * 64;
        #pragma unroll
        for (int j = 0; j < 4; ++j)
            gload16(S + ((size_t)k * NN + rA[j]) * 256 + ci0 + colA, &Ap[(w * 4 + j) * 512]);
        const short* b = bbase + (size_t)kt * 8192;
        #pragma unroll
        for (int j = 0; j < 4; ++j)
            gload16(b + j * 512, &Bw[(w * 4 + j) * 512]);
        __syncthreads();
        #pragma unroll
        for (int ks = 0; ks < 2; ++ks) {
            const int c = (ks * 32 + lq * 8) ^ rswz;
            short8 a[4], bf[4];
            #pragma unroll
            for (int m = 0; m < 4; ++m)
                a[m] = *(const short8*)&Ap[(wr * 64 + m * 16 + lm) * 64 + c];
            #pragma unroll
            for (int nb = 0; nb < 4; ++nb)
                bf[nb] = *(const short8*)&Bw[(wc * 64 + nb * 16 + lm) * 64 + c];
            #pragma unroll
            for (int m = 0; m < 4; ++m)
            #pragma unroll
            for (int nb = 0; nb < 4; ++nb)
                acc[m][nb] = MFMA16(a[m], bf[nb], acc[m][nb], 0, 0, 0);
        }
        __syncthreads();
    }
    #pragma unroll
    for (int m = 0; m < 4; ++m)
    #pragma unroll
    for (int nb = 0; nb < 4; ++nb) {
        int co = co0 + wc * 64 + nb * 16 + lm;
        int n = n0 + wr * 64 + m * 16 + lq * 4;
        short4v o;
        #pragma unroll
        for (int j = 0; j < 4; ++j) o[j] = f2bf(acc[m][nb][j]);
        *(short4v*)(P + ((size_t)split * 256 + co) * NN + n) = o;
    }
}

// ---------------------------------------------------------------- reduces (bf16 partials -> f32 sum)
template<bool RELU>
__global__ __launch_bounds__(256) void reduce_k(
    const short* __restrict__ P, const float* __restrict__ bias,
    float* __restrict__ dst, int Cout, int CP)
{
    int id = blockIdx.x * 256 + threadIdx.x;
    int total = Cout * (NN / 4);
    if (id >= total) return;
    int co = id / (NN / 4), n4 = id - co * (NN / 4);
    const short* p0 = P + ((size_t)co) * NN + n4 * 4;
    float v[4] = {};
    #pragma unroll
    for (int s = 0; s < NSPLIT; ++s) {
        short4v u = *(const short4v*)(p0 + (size_t)s * CP * NN);
        #pragma unroll
        for (int q = 0; q < 4; ++q) v[q] += bf2f(u[q]);
    }
    float bv = bias[co];
    f32x4 o;
    #pragma unroll
    for (int q = 0; q < 4; ++q) {
        float f = v[q] + bv;
        if (RELU) f = fmaxf(f, 0.f);
        o[q] = f;
    }
    *(f32x4*)(dst + (size_t)co * NN + n4 * 4) = o;
}

// bf16 3D-padded transposed output (h layers): bias+relu+cvt+transpose fused
__global__ __launch_bounds__(256) void reduce_bf3(
    const short* __restrict__ P, const float* __restrict__ bias,
    short* __restrict__ dst)
{
    __shared__ float T[64][65];
    const int lane = threadIdx.x & 63, wave = threadIdx.x >> 6;
    const int n0 = blockIdx.x * 64, co0 = blockIdx.y * 64;
    #pragma unroll
    for (int j = 0; j < 16; ++j) {
        int co_l = wave * 16 + j, co = co0 + co_l;
        const short* p0 = P + (size_t)co * NN + n0 + lane;
        float a = 0.f;
        #pragma unroll
        for (int s = 0; s < NSPLIT; ++s) a += bf2f(p0[(size_t)s * 256 * NN]);
        T[co_l][lane] = fmaxf(a + bias[co], 0.f);
    }
    __syncthreads();
    #pragma unroll
    for (int j = 0; j < 16; ++j) {
        int n_l = wave * 16 + j;
        dst[(size_t)n3_of(n0 + n_l) * 256 + co0 + lane] = f2bf(T[lane][n_l]);
    }
}

// ----------------------------------------------------------------
extern "C" void kernel_launch(void* const* d_in, const int* in_sizes, int n_in,
                              void* d_out, int out_size, void* d_ws, size_t ws_size,
                              hipStream_t stream)
{
    const float* x   = (const float*)d_in[0];
    const float* l1w = (const float*)d_in[1];
    const float* l1b = (const float*)d_in[2];
    const float* l2w = (const float*)d_in[3];
    const float* l2b = (const float*)d_in[4];
    const float* l3w = (const float*)d_in[5];
    const float* l3b = (const float*)d_in[6];
    const float* dfw = (const float*)d_in[7];
    const float* dfb = (const float*)d_in[8];
    const float* c3w = (const float*)d_in[9];
    const float* c3b = (const float*)d_in[10];
    float* out = (float*)d_out;

    // ---- workspace ----
    // Overlay region [0, 63.7MB): S (sample phase) over conv-phase-only buffers.
    char* base = (char*)d_ws;
    short* S    = (short*)base;                              // 27*NN*256*2 = 63,700,992
    short* h1b  = (short*)(base);                            // 3,461,120 each (h2b/h3b follow)
    short* wrb1 = (short*)(base + 10383360);                 // 3,538,944 each
    short* wrb2 = (short*)(base + 13922304);
    short* wrb3 = (short*)(base + 17461248);
    short* wrbd = (short*)(base + 21000192);                 // 1,769,472 (ends 22.77MB < 63.7MB)
    short* h2b  = (short*)(base + 3461120);
    short* h3b  = (short*)(base + 6922240);
    // Non-overlaid region (live across the sample phase):
    char* q = base + 63700992;
    short* xbf3 = (short*)q; q += 3461120;                   // N3*256*2
    short* wrbc = (short*)q; q += 3538944;                   // 256*KDIM*2
    short* P    = (short*)q;                                 // 9*256*NN*2 = 21,233,664

    const dim3 blk(256);
    // one prep launch: 5 repacks + transpose + pad-zeroing
    prep_k<<<dim3(288, 7), blk, 0, stream>>>(x, l1w, l2w, l3w, c3w, dfw,
                                             wrb1, wrb2, wrb3, wrbc, wrbd,
                                             xbf3, h1b);

    const int rg256 = (256 * (NN / 4) + 255) / 256;   // 1152

    gemm_conv_sk<256><<<dim3(36, 2, NSPLIT), blk, 0, stream>>>(xbf3, wrb1, P);
    reduce_bf3       <<<dim3(72, 4),         blk, 0, stream>>>(P, l1b, h1b);
    gemm_conv_sk<256><<<dim3(36, 2, NSPLIT), blk, 0, stream>>>(h1b, wrb2, P);
    reduce_bf3       <<<dim3(72, 4),         blk, 0, stream>>>(P, l2b, h2b);
    gemm_conv_sk<256><<<dim3(36, 2, NSPLIT), blk, 0, stream>>>(h2b, wrb3, P);
    reduce_bf3       <<<dim3(72, 4),         blk, 0, stream>>>(P, l3b, h3b);
    gemm_conv_sk<128><<<dim3(36, 1, NSPLIT), blk, 0, stream>>>(h3b, wrbd, P);

    // offsets-reduce folded into sample_k (reads bf16 partials + dfb directly)
    sample_k<<<dim3(72, 27), blk, 0, stream>>>(xbf3, P, dfb, S);
    gemm_deform_sk<<<dim3(36, 2, NSPLIT), blk, 0, stream>>>(S, wrbc, P);
    reduce_k<false><<<dim3(rg256), blk, 0, stream>>>(P, c3b, out, 256, 256);
}